// Round 6
// baseline (448.249 us; speedup 1.0000x reference)
//
#include <hip/hip_runtime.h>

#define GG 256   // NUM_GRAPHS
#define ZZDIM 32 // Z
#define KK 64    // K
#define EMBD 10  // EMB
#define TILE (GG * ZZDIM)  // 8192 floats = 32 KB
#define NB 8               // row buckets = XCDs
#define SBLK 512           // scatter grid (must be multiple of 8)

// NOTE: record packing assumes n < 2^17 (n = 100000) and g < 256.

// ---------------- kernels ----------------

// deg[i] = 2.0 (improved self-loop fill); zero bucket counters
__global__ void init_kernel(float* __restrict__ deg, int* __restrict__ bcnt, int n) {
    int i = blockIdx.x * blockDim.x + threadIdx.x;
    if (i < n) deg[i] = 2.0f;
    if (i < NB) bcnt[i] = 0;
}

// deg[col[e]] += w[e], 4 edges/thread
__global__ void deg_kernel(const int* __restrict__ col, const float* __restrict__ w,
                           float* __restrict__ deg, int e) {
    int i = (blockIdx.x * blockDim.x + threadIdx.x) * 4;
    if (i + 3 < e) {
        int4 c4 = *(const int4*)(col + i);
        float4 w4 = *(const float4*)(w + i);
        atomicAdd(&deg[c4.x], w4.x);
        atomicAdd(&deg[c4.y], w4.y);
        atomicAdd(&deg[c4.z], w4.z);
        atomicAdd(&deg[c4.w], w4.w);
    } else {
        for (; i < e; ++i) atomicAdd(&deg[col[i]], w[i]);
    }
}

// hs[i,z] = rsqrt(deg[i]) * sum_j embed[x[i],j] * Wc[j,z]
// nd[i] = (dinv_i, bitcast(batch_i))
__global__ void hs_kernel(const int* __restrict__ x, const float* __restrict__ emb,
                          const float* __restrict__ Wc, const float* __restrict__ deg,
                          const int* __restrict__ batch, float2* __restrict__ nd,
                          float* __restrict__ hs, int n) {
    int tid = blockIdx.x * blockDim.x + threadIdx.x;
    int i = tid >> 5, z = tid & 31;
    if (i >= n) return;
    float d = rsqrtf(deg[i]);            // deg >= 2 always
    if (z == 0) nd[i] = make_float2(d, __int_as_float(batch[i]));
    int xi = x[i];
    const float* er = emb + (long)xi * EMBD;
    float acc = 0.f;
#pragma unroll
    for (int j = 0; j < EMBD; ++j) acc += er[j] * Wc[j * ZZDIM + z];
    hs[(long)i * ZZDIM + z] = d * acc;
}

// exact per-bucket histogram (per-wave LDS counters -> global)
__global__ void hist_kernel(const int* __restrict__ row, int* __restrict__ bcnt,
                            int e, int n) {
    __shared__ int h[4 * NB];            // 256 threads = 4 waves
    if (threadIdx.x < 4 * NB) h[threadIdx.x] = 0;
    __syncthreads();
    int wv = threadIdx.x >> 6;
    for (long i = blockIdx.x * (long)blockDim.x + threadIdx.x; i < e;
         i += (long)gridDim.x * blockDim.x) {
        unsigned b = ((unsigned)row[i] * 8u) / (unsigned)n;
        atomicAdd(&h[wv * NB + b], 1);
    }
    __syncthreads();
    if (threadIdx.x < NB) {
        int s = h[threadIdx.x] + h[NB + threadIdx.x] + h[2 * NB + threadIdx.x] +
                h[3 * NB + threadIdx.x];
        if (s) atomicAdd(&bcnt[threadIdx.x], s);
    }
}

// exclusive scan of 8 bucket counts; init cursors
__global__ void scan_kernel(const int* __restrict__ bcnt, int* __restrict__ bbase,
                            int* __restrict__ bcur) {
    if (threadIdx.x == 0) {
        int s = 0;
        for (int b = 0; b < NB; ++b) { bbase[b] = s; bcur[b] = s; s += bcnt[b]; }
        bbase[NB] = s;
    }
}

// scatter edges into row-buckets: rec[slot] = (w*dinv[col], pack(g<<17|row))
__global__ void bucket_kernel(const int* __restrict__ row, const int* __restrict__ col,
                              const float* __restrict__ w, const float2* __restrict__ nd,
                              int* __restrict__ bcur, float2* __restrict__ rec,
                              int e, int n) {
    __shared__ int lcnt[NB];
    __shared__ int lres[NB];
    __shared__ int loff[NB];
    if (threadIdx.x < NB) { lcnt[threadIdx.x] = 0; loff[threadIdx.x] = 0; }
    __syncthreads();
    const long start = (long)blockIdx.x * 2048;
    int myb[8];
#pragma unroll
    for (int k = 0; k < 8; ++k) {
        long i = start + k * 256 + threadIdx.x;
        int b = -1;
        if (i < e) {
            b = (int)(((unsigned)row[i] * 8u) / (unsigned)n);
            atomicAdd(&lcnt[b], 1);
        }
        myb[k] = b;
    }
    __syncthreads();
    if (threadIdx.x < NB) lres[threadIdx.x] = atomicAdd(&bcur[threadIdx.x], lcnt[threadIdx.x]);
    __syncthreads();
#pragma unroll
    for (int k = 0; k < 8; ++k) {
        long i = start + k * 256 + threadIdx.x;
        if (i < e) {
            int b = myb[k];
            int slot = lres[b] + atomicAdd(&loff[b], 1);
            int c = col[i];
            float2 ndc = nd[c];
            float coeff = w[i] * ndc.x;
            unsigned pr = ((unsigned)__float_as_int(ndc.y) << 17) | (unsigned)row[i];
            rec[slot] = make_float2(coeff, __int_as_float((int)pr));
        }
    }
}

// counts via binary search on sorted batch
__global__ void cnt_kernel(const int* __restrict__ batch, float* __restrict__ cnt, int n) {
    __shared__ int lb[GG + 1];
    int g = threadIdx.x;  // 256 threads
    int lo = 0, hi = n;
    while (lo < hi) {
        int mid = (lo + hi) >> 1;
        if (batch[mid] < g) lo = mid + 1; else hi = mid;
    }
    lb[g] = lo;
    if (g == 0) lb[GG] = n;
    __syncthreads();
    cnt[g] = (float)(lb[g + 1] - lb[g]);
}

// block blockIdx processes bucket (blockIdx % 8) only -> its hs gathers stay in a
// 1.6 MB row-slice that fits the XCD-local L2 (blockIdx%8 ~ XCD round-robin).
__global__ void __launch_bounds__(512) scatter_kernel(
    const float2* __restrict__ rec, const int* __restrict__ bbase,
    const float2* __restrict__ nd, const float* __restrict__ hs,
    float* __restrict__ partial, int e, int n) {
    __shared__ float s[TILE];
    for (int i = threadIdx.x; i < TILE; i += 512) s[i] = 0.f;
    __syncthreads();

    const int z = threadIdx.x & 31;
    const int grpL = threadIdx.x >> 5;          // 0..15
    const int b = blockIdx.x & 7;               // bucket = XCD
    const int blkB = blockIdx.x >> 3;           // block index within bucket
    const int bpb = gridDim.x >> 3;             // blocks per bucket
    const long lo = bbase[b], hi = bbase[b + 1];

    // bucketed edges: 8 records per group-iteration (8 hs gathers in flight)
    const long gstride = (long)bpb * 16 * 8;
    for (long it = lo + (blkB * 16L + grpL) * 8; it + 7 < hi; it += gstride) {
        float4 r01 = *(const float4*)(rec + it);
        float4 r23 = *(const float4*)(rec + it + 2);
        float4 r45 = *(const float4*)(rec + it + 4);
        float4 r67 = *(const float4*)(rec + it + 6);
        unsigned p0 = (unsigned)__float_as_int(r01.y), p1 = (unsigned)__float_as_int(r01.w);
        unsigned p2 = (unsigned)__float_as_int(r23.y), p3 = (unsigned)__float_as_int(r23.w);
        unsigned p4 = (unsigned)__float_as_int(r45.y), p5 = (unsigned)__float_as_int(r45.w);
        unsigned p6 = (unsigned)__float_as_int(r67.y), p7 = (unsigned)__float_as_int(r67.w);
        float v0 = hs[(long)(p0 & 0x1FFFFu) * ZZDIM + z];
        float v1 = hs[(long)(p1 & 0x1FFFFu) * ZZDIM + z];
        float v2 = hs[(long)(p2 & 0x1FFFFu) * ZZDIM + z];
        float v3 = hs[(long)(p3 & 0x1FFFFu) * ZZDIM + z];
        float v4 = hs[(long)(p4 & 0x1FFFFu) * ZZDIM + z];
        float v5 = hs[(long)(p5 & 0x1FFFFu) * ZZDIM + z];
        float v6 = hs[(long)(p6 & 0x1FFFFu) * ZZDIM + z];
        float v7 = hs[(long)(p7 & 0x1FFFFu) * ZZDIM + z];
        atomicAdd(&s[(p0 >> 17) * ZZDIM + z], r01.x * v0);
        atomicAdd(&s[(p1 >> 17) * ZZDIM + z], r01.z * v1);
        atomicAdd(&s[(p2 >> 17) * ZZDIM + z], r23.x * v2);
        atomicAdd(&s[(p3 >> 17) * ZZDIM + z], r23.z * v3);
        atomicAdd(&s[(p4 >> 17) * ZZDIM + z], r45.x * v4);
        atomicAdd(&s[(p5 >> 17) * ZZDIM + z], r45.z * v5);
        atomicAdd(&s[(p6 >> 17) * ZZDIM + z], r67.x * v6);
        atomicAdd(&s[(p7 >> 17) * ZZDIM + z], r67.z * v7);
    }
    // bucket tail (< 8 records): one group handles it
    if (blkB == 0 && grpL == 0) {
        for (long it = lo + ((hi - lo) & ~7L); it < hi; ++it) {
            float2 r = rec[it];
            unsigned p = (unsigned)__float_as_int(r.y);
            float v = hs[(long)(p & 0x1FFFFu) * ZZDIM + z];
            atomicAdd(&s[(p >> 17) * ZZDIM + z], r.x * v);
        }
    }

    // self-loops of this bucket's node slice: 2*dinv[i]*hs[i] into batch[i]
    const long ss = ((long)b * n + 7) / 8, se = ((long)(b + 1) * n + 7) / 8;
    const long sstride = (long)bpb * 16 * 4;
    for (long i = ss + (blkB * 16L + grpL) * 4; i + 3 < se; i += sstride) {
        float2 n0 = nd[i], n1 = nd[i + 1], n2 = nd[i + 2], n3 = nd[i + 3];
        float v0 = hs[(i + 0) * ZZDIM + z];
        float v1 = hs[(i + 1) * ZZDIM + z];
        float v2 = hs[(i + 2) * ZZDIM + z];
        float v3 = hs[(i + 3) * ZZDIM + z];
        atomicAdd(&s[__float_as_int(n0.y) * ZZDIM + z], 2.0f * n0.x * v0);
        atomicAdd(&s[__float_as_int(n1.y) * ZZDIM + z], 2.0f * n1.x * v1);
        atomicAdd(&s[__float_as_int(n2.y) * ZZDIM + z], 2.0f * n2.x * v2);
        atomicAdd(&s[__float_as_int(n3.y) * ZZDIM + z], 2.0f * n3.x * v3);
    }
    if (blkB == 0 && grpL == 0) {
        for (long i = ss + ((se - ss) & ~3L); i < se; ++i) {
            float2 n0 = nd[i];
            float v = hs[i * ZZDIM + z];
            atomicAdd(&s[__float_as_int(n0.y) * ZZDIM + z], 2.0f * n0.x * v);
        }
    }

    __syncthreads();
    float* r0 = partial + (long)blockIdx.x * TILE;
    for (int idx = threadIdx.x; idx < TILE; idx += 512)
        r0[idx] = s[idx];   // plain coalesced store
}

// reduce partials -> pooled -> logits
__global__ void __launch_bounds__(256) finalize_kernel(
    const float* __restrict__ partial, int nblocks, const float* __restrict__ cnt,
    const float* __restrict__ bc, const float* __restrict__ Wr, float* __restrict__ out) {
    int g = blockIdx.x;
    int t = threadIdx.x;
    int j = t >> 5, z = t & 31;
    __shared__ float sacc[8][ZZDIM];
    __shared__ float p[ZZDIM];

    const float* q = partial + g * ZZDIM + z;
    float acc = 0.f;
    for (int r = j; r < nblocks; r += 8)
        acc += q[(long)r * TILE];
    sacc[j][z] = acc;
    __syncthreads();

    if (t < ZZDIM) {
        float a = 0.f;
#pragma unroll
        for (int jj = 0; jj < 8; ++jj) a += sacc[jj][t];
        float c = cnt[g];
        float v = (c > 0.f) ? (bc[t] + a / c) : 0.f;
        out[g * ZZDIM + t] = v;
        p[t] = v;
    }
    __syncthreads();
    if (t < KK) {
        float a = 0.f;
#pragma unroll
        for (int zz = 0; zz < ZZDIM; ++zz) a += p[zz] * Wr[zz * KK + t];
        out[GG * ZZDIM + g * KK + t] = a;
    }
}

// ---------------- launch ----------------

extern "C" void kernel_launch(void* const* d_in, const int* in_sizes, int n_in,
                              void* d_out, int out_size, void* d_ws, size_t ws_size,
                              hipStream_t stream) {
    const int*   x     = (const int*)d_in[0];
    const int*   ei    = (const int*)d_in[1];   // [2,E]: rows then cols
    const float* ew    = (const float*)d_in[2];
    const int*   batch = (const int*)d_in[3];
    const float* emb   = (const float*)d_in[4];
    const float* Wc    = (const float*)d_in[5];
    const float* bc    = (const float*)d_in[6];
    const float* Wr    = (const float*)d_in[7];
    float* out = (float*)d_out;

    const int n = in_sizes[0];
    const int e = in_sizes[2];

    float* ws   = (float*)d_ws;
    float* deg  = ws;                        // n
    float* hs   = ws + n;                    // 32n (128 B rows, line-aligned)
    float2* nd  = (float2*)(ws + 33L * n);   // n float2
    float* cnt  = ws + 35L * n;              // GG
    int*  bcnt  = (int*)(cnt + GG);          // 8
    int*  bbase = bcnt + NB;                 // 9
    int*  bcur  = bbase + NB + 1;            // 8
    long base = 35L * n + GG + 32;
    base = (base + 63) & ~63L;
    float2* rec = (float2*)(ws + base);      // e records (8 B each)
    long pbase = base + 2L * e;
    pbase = (pbase + 63) & ~63L;
    float* partial = ws + pbase;

    long avail = (long)(ws_size / 4) - pbase;
    int nblocks = (int)(avail / TILE);
    if (nblocks > SBLK) nblocks = SBLK;
    nblocks &= ~7;                           // multiple of 8 buckets
    if (nblocks < 64) nblocks = 64;

    init_kernel<<<(n + 255) / 256, 256, 0, stream>>>(deg, bcnt, n);
    deg_kernel<<<(e / 4 + 255) / 256, 256, 0, stream>>>(ei + e, ew, deg, e);
    hs_kernel<<<(n * 32 + 255) / 256, 256, 0, stream>>>(x, emb, Wc, deg, batch, nd, hs, n);
    hist_kernel<<<256, 256, 0, stream>>>(ei, bcnt, e, n);
    scan_kernel<<<1, 64, 0, stream>>>(bcnt, bbase, bcur);
    cnt_kernel<<<1, 256, 0, stream>>>(batch, cnt, n);
    bucket_kernel<<<(e + 2047) / 2048, 256, 0, stream>>>(ei, ei + e, ew, nd, bcur, rec, e, n);
    scatter_kernel<<<nblocks, 512, 0, stream>>>(rec, bbase, nd, hs, partial, e, n);
    finalize_kernel<<<GG, 256, 0, stream>>>(partial, nblocks, cnt, bc, Wr, out);
}

// Round 7
// 193.654 us; speedup vs baseline: 2.3147x; 2.3147x over previous
//
#include <hip/hip_runtime.h>

#define GG 256   // NUM_GRAPHS
#define ZZDIM 32 // Z
#define KK 64    // K
#define EMBD 10  // EMB
#define BPG 4                // scatter blocks per graph
#define SGRID (GG * BPG)     // 1024 scatter blocks
#define SLOTS 64             // slots per 512-thr scatter block (8 lanes each)
#define SPG (BPG * SLOTS)    // 256 slots per graph

// ---------------- kernels ----------------

// deg[i] = 2.0 (improved self-loop fill); zero graph-bucket counters
__global__ void init_kernel(float* __restrict__ deg, int* __restrict__ gcnt, int n) {
    int i = blockIdx.x * blockDim.x + threadIdx.x;
    if (i < n) deg[i] = 2.0f;
    if (i < GG) gcnt[i] = 0;
}

// deg[col[e]] += w[e], 4 edges/thread
__global__ void deg_kernel(const int* __restrict__ col, const float* __restrict__ w,
                           float* __restrict__ deg, int e) {
    int i = (blockIdx.x * blockDim.x + threadIdx.x) * 4;
    if (i + 3 < e) {
        int4 c4 = *(const int4*)(col + i);
        float4 w4 = *(const float4*)(w + i);
        atomicAdd(&deg[c4.x], w4.x);
        atomicAdd(&deg[c4.y], w4.y);
        atomicAdd(&deg[c4.z], w4.z);
        atomicAdd(&deg[c4.w], w4.w);
    } else {
        for (; i < e; ++i) atomicAdd(&deg[col[i]], w[i]);
    }
}

// hs[i,z] = rsqrt(deg[i]) * sum_j embed[x[i],j] * Wc[j,z];  nd[i] = (dinv_i, bits(batch_i))
__global__ void hs_kernel(const int* __restrict__ x, const float* __restrict__ emb,
                          const float* __restrict__ Wc, const float* __restrict__ deg,
                          const int* __restrict__ batch, float2* __restrict__ nd,
                          float* __restrict__ hs, int n) {
    int tid = blockIdx.x * blockDim.x + threadIdx.x;
    int i = tid >> 5, z = tid & 31;
    if (i >= n) return;
    float d = rsqrtf(deg[i]);            // deg >= 2 always
    if (z == 0) nd[i] = make_float2(d, __int_as_float(batch[i]));
    int xi = x[i];
    const float* er = emb + (long)xi * EMBD;
    float acc = 0.f;
#pragma unroll
    for (int j = 0; j < EMBD; ++j) acc += er[j] * Wc[j * ZZDIM + z];
    hs[(long)i * ZZDIM + z] = d * acc;
}

// per-graph edge histogram: g = batch[col[i]]
__global__ void hist_kernel(const int* __restrict__ col, const int* __restrict__ batch,
                            int* __restrict__ gcnt, int e) {
    __shared__ int h[GG];
    if (threadIdx.x < GG) h[threadIdx.x] = 0;
    __syncthreads();
    for (long i = blockIdx.x * (long)blockDim.x + threadIdx.x; i < e;
         i += (long)gridDim.x * blockDim.x)
        atomicAdd(&h[batch[col[i]]], 1);
    __syncthreads();
    if (threadIdx.x < GG && h[threadIdx.x])
        atomicAdd(&gcnt[threadIdx.x], h[threadIdx.x]);
}

// exclusive scan of 256 bucket counts; init cursors
__global__ void scan_kernel(const int* __restrict__ gcnt, int* __restrict__ gbase,
                            int* __restrict__ gcur) {
    if (threadIdx.x == 0) {
        int s = 0;
        for (int g = 0; g < GG; ++g) { gbase[g] = s; gcur[g] = s; s += gcnt[g]; }
        gbase[GG] = s;
    }
}

// node ranges per graph via binary search on sorted batch
__global__ void lb_kernel(const int* __restrict__ batch, int* __restrict__ lb, int n) {
    int g = threadIdx.x;  // 256 threads
    int lo = 0, hi = n;
    while (lo < hi) {
        int mid = (lo + hi) >> 1;
        if (batch[mid] < g) lo = mid + 1; else hi = mid;
    }
    lb[g] = lo;
    if (g == 0) lb[GG] = n;
}

// counting-sort edges into per-graph buckets: rec[slot] = (w*dinv[col], bits(row))
__global__ void __launch_bounds__(512) bucket_kernel(
    const int* __restrict__ row, const int* __restrict__ col, const float* __restrict__ w,
    const float2* __restrict__ nd, int* __restrict__ gcur, float2* __restrict__ rec, int e) {
    __shared__ int lcnt[GG], lres[GG], loff[GG];
    for (int t = threadIdx.x; t < GG; t += 512) { lcnt[t] = 0; loff[t] = 0; }
    __syncthreads();
    const long start = (long)blockIdx.x * 8192;
    int myg[16]; float myc[16]; int myr[16];
#pragma unroll
    for (int k = 0; k < 16; ++k) {
        long i = start + k * 512 + threadIdx.x;
        int g = -1;
        if (i < e) {
            int c = col[i];
            float2 ndc = nd[c];
            g = __float_as_int(ndc.y);
            myc[k] = w[i] * ndc.x;
            myr[k] = row[i];
            atomicAdd(&lcnt[g], 1);
        }
        myg[k] = g;
    }
    __syncthreads();
    for (int t = threadIdx.x; t < GG; t += 512)
        if (lcnt[t]) lres[t] = atomicAdd(&gcur[t], lcnt[t]);
    __syncthreads();
#pragma unroll
    for (int k = 0; k < 16; ++k) {
        if (myg[k] >= 0) {
            int slot = lres[myg[k]] + atomicAdd(&loff[myg[k]], 1);
            rec[slot] = make_float2(myc[k], __int_as_float(myr[k]));
        }
    }
}

// Register-accumulation scatter: block (g = blk>>2) walks graph g's record list.
// 8 lanes per slot, float4 per lane -> one wave-instr gathers 8 whole hs rows.
// No LDS atomics, no barriers in the loop.
__global__ void __launch_bounds__(512) scatter_kernel(
    const float2* __restrict__ rec, const int* __restrict__ gbase,
    const int* __restrict__ lb, const float2* __restrict__ nd,
    const float4* __restrict__ hs4, float* __restrict__ partial) {
    const int z4   = threadIdx.x & 7;        // channel quad 0..7
    const int slot = threadIdx.x >> 3;       // 0..63
    const int g = blockIdx.x >> 2;
    const int q = blockIdx.x & 3;
    const int sg = q * SLOTS + slot;         // slot-in-graph 0..255

    float4 acc = make_float4(0.f, 0.f, 0.f, 0.f);

    // edges of graph g (bucketed, contiguous)
    const long lo = gbase[g], hi = gbase[g + 1];
    long it = lo + sg;
    for (; it + 3L * SPG < hi; it += 4L * SPG) {
        float2 r0 = rec[it];
        float2 r1 = rec[it + SPG];
        float2 r2 = rec[it + 2L * SPG];
        float2 r3 = rec[it + 3L * SPG];
        float4 v0 = hs4[(long)__float_as_int(r0.y) * 8 + z4];
        float4 v1 = hs4[(long)__float_as_int(r1.y) * 8 + z4];
        float4 v2 = hs4[(long)__float_as_int(r2.y) * 8 + z4];
        float4 v3 = hs4[(long)__float_as_int(r3.y) * 8 + z4];
        acc.x = fmaf(r0.x, v0.x, acc.x); acc.y = fmaf(r0.x, v0.y, acc.y);
        acc.z = fmaf(r0.x, v0.z, acc.z); acc.w = fmaf(r0.x, v0.w, acc.w);
        acc.x = fmaf(r1.x, v1.x, acc.x); acc.y = fmaf(r1.x, v1.y, acc.y);
        acc.z = fmaf(r1.x, v1.z, acc.z); acc.w = fmaf(r1.x, v1.w, acc.w);
        acc.x = fmaf(r2.x, v2.x, acc.x); acc.y = fmaf(r2.x, v2.y, acc.y);
        acc.z = fmaf(r2.x, v2.z, acc.z); acc.w = fmaf(r2.x, v2.w, acc.w);
        acc.x = fmaf(r3.x, v3.x, acc.x); acc.y = fmaf(r3.x, v3.y, acc.y);
        acc.z = fmaf(r3.x, v3.z, acc.z); acc.w = fmaf(r3.x, v3.w, acc.w);
    }
    for (; it < hi; it += SPG) {
        float2 r = rec[it];
        float4 v = hs4[(long)__float_as_int(r.y) * 8 + z4];
        acc.x = fmaf(r.x, v.x, acc.x); acc.y = fmaf(r.x, v.y, acc.y);
        acc.z = fmaf(r.x, v.z, acc.z); acc.w = fmaf(r.x, v.w, acc.w);
    }

    // self-loops: nodes of graph g are contiguous [lb[g], lb[g+1])
    const long ns = lb[g], ne = lb[g + 1];
    for (long i = ns + sg; i < ne; i += SPG) {
        float c2 = 2.0f * nd[i].x;
        float4 v = hs4[i * 8 + z4];
        acc.x = fmaf(c2, v.x, acc.x); acc.y = fmaf(c2, v.y, acc.y);
        acc.z = fmaf(c2, v.z, acc.z); acc.w = fmaf(c2, v.w, acc.w);
    }

    // reduce 64 slots -> 32 channels
    __shared__ float4 s[SLOTS][8];
    __shared__ float4 s2[8][8];
    s[slot][z4] = acc;
    __syncthreads();
    if (threadIdx.x < 64) {
        int j = threadIdx.x & 7, part = threadIdx.x >> 3;
        float4 a = make_float4(0.f, 0.f, 0.f, 0.f);
#pragma unroll
        for (int k = 0; k < 8; ++k) {
            float4 b = s[part * 8 + k][j];
            a.x += b.x; a.y += b.y; a.z += b.z; a.w += b.w;
        }
        s2[part][j] = a;
    }
    __syncthreads();
    if (threadIdx.x < 8) {
        int j = threadIdx.x;
        float4 a = make_float4(0.f, 0.f, 0.f, 0.f);
#pragma unroll
        for (int k = 0; k < 8; ++k) {
            float4 b = s2[k][j];
            a.x += b.x; a.y += b.y; a.z += b.z; a.w += b.w;
        }
        *(float4*)&partial[(long)blockIdx.x * ZZDIM + j * 4] = a;
    }
}

// sum BPG partials per graph -> pooled -> logits
__global__ void finalize_kernel(const float* __restrict__ partial, const int* __restrict__ lb,
                                const float* __restrict__ bc, const float* __restrict__ Wr,
                                float* __restrict__ out) {
    int g = blockIdx.x;
    int t = threadIdx.x;  // 64 threads
    __shared__ float p[ZZDIM];
    if (t < ZZDIM) {
        float a = 0.f;
#pragma unroll
        for (int q = 0; q < BPG; ++q) a += partial[(long)(g * BPG + q) * ZZDIM + t];
        float c = (float)(lb[g + 1] - lb[g]);
        float v = (c > 0.f) ? (bc[t] + a / c) : 0.f;
        out[g * ZZDIM + t] = v;
        p[t] = v;
    }
    __syncthreads();
    float a = 0.f;
#pragma unroll
    for (int zz = 0; zz < ZZDIM; ++zz) a += p[zz] * Wr[zz * KK + t];
    out[GG * ZZDIM + g * KK + t] = a;
}

// ---------------- launch ----------------

extern "C" void kernel_launch(void* const* d_in, const int* in_sizes, int n_in,
                              void* d_out, int out_size, void* d_ws, size_t ws_size,
                              hipStream_t stream) {
    const int*   x     = (const int*)d_in[0];
    const int*   ei    = (const int*)d_in[1];   // [2,E]: rows then cols
    const float* ew    = (const float*)d_in[2];
    const int*   batch = (const int*)d_in[3];
    const float* emb   = (const float*)d_in[4];
    const float* Wc    = (const float*)d_in[5];
    const float* bc    = (const float*)d_in[6];
    const float* Wr    = (const float*)d_in[7];
    float* out = (float*)d_out;

    const int n = in_sizes[0];
    const int e = in_sizes[2];

    float* ws   = (float*)d_ws;
    float* hs   = ws;                        // 32n (16 B-aligned: base of ws)
    float* deg  = ws + 32L * n;              // n
    float2* nd  = (float2*)(ws + 33L * n);   // n float2 (33n even -> 8 B aligned)
    int*  lb    = (int*)(ws + 35L * n);      // GG+1
    int*  gcnt  = lb + GG + 1;               // GG
    int*  gbase = gcnt + GG;                 // GG+1
    int*  gcur  = gbase + GG + 1;            // GG
    long base = 35L * n + (4 * GG + 2);
    base = (base + 63) & ~63L;               // align rec
    float2* rec = (float2*)(ws + base);      // e records (8 B)
    long pbase = base + 2L * e;
    pbase = (pbase + 63) & ~63L;
    float* partial = ws + pbase;             // SGRID*32 floats

    init_kernel<<<(n + 255) / 256, 256, 0, stream>>>(deg, gcnt, n);
    deg_kernel<<<(e / 4 + 255) / 256, 256, 0, stream>>>(ei + e, ew, deg, e);
    hs_kernel<<<(n * 32 + 255) / 256, 256, 0, stream>>>(x, emb, Wc, deg, batch, nd, hs, n);
    hist_kernel<<<256, 256, 0, stream>>>(ei + e, batch, gcnt, e);
    scan_kernel<<<1, 64, 0, stream>>>(gcnt, gbase, gcur);
    lb_kernel<<<1, 256, 0, stream>>>(batch, lb, n);
    bucket_kernel<<<(e + 8191) / 8192, 512, 0, stream>>>(ei, ei + e, ew, nd, gcur, rec, e);
    scatter_kernel<<<SGRID, 512, 0, stream>>>(rec, gbase, lb, nd, (const float4*)hs, partial);
    finalize_kernel<<<GG, KK, 0, stream>>>(partial, lb, bc, Wr, out);
}

// Round 8
// 112.929 us; speedup vs baseline: 3.9693x; 1.7148x over previous
//
#include <hip/hip_runtime.h>

#define GG 256   // NUM_GRAPHS
#define ZZDIM 32 // Z
#define KK 64    // K
#define EMBD 10  // EMB
#define BPG 4                // scatter blocks per graph
#define SGRID (GG * BPG)     // 1024 scatter blocks
#define SLOTS 64             // slots per 512-thr scatter block (8 lanes each)
#define SPG (BPG * SLOTS)    // 256 slots per graph
#define MAXN 4096            // LDS node-slice capacity (graphs avg ~390 nodes; global fallback past this)

// Record: rec[i] = (w, bits(colLocal<<17 | row)); row < 2^17 (n=100000), colLocal < 2^15.

// ---------------- kernels ----------------

// node ranges per graph via binary search on sorted batch; zero bucket counters
__global__ void lb_kernel(const int* __restrict__ batch, int* __restrict__ lb,
                          int* __restrict__ gcnt, int n) {
    int g = threadIdx.x;  // 256 threads
    int lo = 0, hi = n;
    while (lo < hi) {
        int mid = (lo + hi) >> 1;
        if (batch[mid] < g) lo = mid + 1; else hi = mid;
    }
    lb[g] = lo;
    if (g == 0) lb[GG] = n;
    gcnt[g] = 0;
}

// per-graph edge histogram; memoize g per edge (ge) for the bucket pass
__global__ void hist_kernel(const int* __restrict__ col, const int* __restrict__ batch,
                            unsigned char* __restrict__ ge, int* __restrict__ gcnt, int e) {
    __shared__ int h[GG];
    if (threadIdx.x < GG) h[threadIdx.x] = 0;
    __syncthreads();
    for (long i = blockIdx.x * (long)blockDim.x + threadIdx.x; i < e;
         i += (long)gridDim.x * blockDim.x) {
        int g = batch[col[i]];
        ge[i] = (unsigned char)g;
        atomicAdd(&h[g], 1);
    }
    __syncthreads();
    if (threadIdx.x < GG && h[threadIdx.x])
        atomicAdd(&gcnt[threadIdx.x], h[threadIdx.x]);
}

// exclusive scan of 256 bucket counts; init cursors
__global__ void scan_kernel(const int* __restrict__ gcnt, int* __restrict__ gbase,
                            int* __restrict__ gcur) {
    if (threadIdx.x == 0) {
        int s = 0;
        for (int g = 0; g < GG; ++g) { gbase[g] = s; gcur[g] = s; s += gcnt[g]; }
        gbase[GG] = s;
    }
}

// counting-sort edges into per-graph buckets: rec = (w, bits(colLocal<<17|row))
__global__ void __launch_bounds__(512) bucket_kernel(
    const int* __restrict__ row, const int* __restrict__ col, const float* __restrict__ w,
    const unsigned char* __restrict__ ge, const int* __restrict__ lb,
    int* __restrict__ gcur, float2* __restrict__ rec, int e) {
    __shared__ int lcnt[GG], lres[GG], loff[GG], lbs[GG];
    for (int t = threadIdx.x; t < GG; t += 512) { lcnt[t] = 0; loff[t] = 0; lbs[t] = lb[t]; }
    __syncthreads();
    const long start = (long)blockIdx.x * 8192;
    int myg[16];
#pragma unroll
    for (int k = 0; k < 16; ++k) {
        long i = start + k * 512 + threadIdx.x;
        int g = -1;
        if (i < e) { g = ge[i]; atomicAdd(&lcnt[g], 1); }
        myg[k] = g;
    }
    __syncthreads();
    for (int t = threadIdx.x; t < GG; t += 512)
        if (lcnt[t]) lres[t] = atomicAdd(&gcur[t], lcnt[t]);
    __syncthreads();
#pragma unroll
    for (int k = 0; k < 16; ++k) {
        long i = start + k * 512 + threadIdx.x;
        if (i < e) {
            int g = myg[k];
            int slot = lres[g] + atomicAdd(&loff[g], 1);
            unsigned p = ((unsigned)(col[i] - lbs[g]) << 17) | (unsigned)row[i];
            rec[slot] = make_float2(w[i], __int_as_float((int)p));
        }
    }
}

// per-graph degree via LDS accumulation over the graph's contiguous node slice;
// writes dinv = rsqrt(deg). One block per graph — NO device-scope atomics.
__global__ void degB_kernel(const float2* __restrict__ rec, const int* __restrict__ gbase,
                            const int* __restrict__ lb, float* __restrict__ dinv) {
    __shared__ float dl[MAXN];
    const int g = blockIdx.x;
    const int ns = lb[g], ne = lb[g + 1], sz = ne - ns;
    const long lo = gbase[g], hi = gbase[g + 1];
    if (sz <= MAXN) {
        for (int t = threadIdx.x; t < sz; t += 256) dl[t] = 2.0f;  // improved self-loop fill
        __syncthreads();
        for (long it = lo + threadIdx.x; it < hi; it += 256) {
            float2 r = rec[it];
            atomicAdd(&dl[(unsigned)__float_as_int(r.y) >> 17], r.x);
        }
        __syncthreads();
        for (int t = threadIdx.x; t < sz; t += 256) dinv[ns + t] = rsqrtf(dl[t]);
    } else {  // fallback (never expected at n/GG ~ 390): block-private global accumulation
        for (int t = threadIdx.x; t < sz; t += 256) dinv[ns + t] = 2.0f;
        __syncthreads();
        for (long it = lo + threadIdx.x; it < hi; it += 256) {
            float2 r = rec[it];
            atomicAdd(&dinv[ns + ((unsigned)__float_as_int(r.y) >> 17)], r.x);
        }
        __syncthreads();
        for (int t = threadIdx.x; t < sz; t += 256) dinv[ns + t] = rsqrtf(dinv[ns + t]);
    }
}

// hs[i,z] = dinv[i] * sum_j embed[x[i],j] * Wc[j,z]
__global__ void hs_kernel(const int* __restrict__ x, const float* __restrict__ emb,
                          const float* __restrict__ Wc, const float* __restrict__ dinv,
                          float* __restrict__ hs, int n) {
    int tid = blockIdx.x * blockDim.x + threadIdx.x;
    int i = tid >> 5, z = tid & 31;
    if (i >= n) return;
    float d = dinv[i];
    int xi = x[i];
    const float* er = emb + (long)xi * EMBD;
    float acc = 0.f;
#pragma unroll
    for (int j = 0; j < EMBD; ++j) acc += er[j] * Wc[j * ZZDIM + z];
    hs[(long)i * ZZDIM + z] = d * acc;
}

// Register-accumulation scatter: block (g = blk>>2) walks graph g's record list.
// coeff = w * dinv[col] from the LDS-staged dinv slice; 8 lanes x float4 per edge.
__global__ void __launch_bounds__(512) scatter_kernel(
    const float2* __restrict__ rec, const int* __restrict__ gbase,
    const int* __restrict__ lb, const float* __restrict__ dinv,
    const float4* __restrict__ hs4, float* __restrict__ partial) {
    __shared__ float dl[MAXN];
    const int z4   = threadIdx.x & 7;        // channel quad 0..7
    const int slot = threadIdx.x >> 3;       // 0..63
    const int g = blockIdx.x >> 2;
    const int q = blockIdx.x & 3;
    const int sg = q * SLOTS + slot;         // slot-in-graph 0..255
    const int ns = lb[g], ne = lb[g + 1], sz = ne - ns;
    const bool inl = (sz <= MAXN);
    if (inl) for (int t = threadIdx.x; t < sz; t += 512) dl[t] = dinv[ns + t];
    __syncthreads();

    float4 acc = make_float4(0.f, 0.f, 0.f, 0.f);

    // edges of graph g (bucketed, contiguous)
    const long lo = gbase[g], hi = gbase[g + 1];
    long it = lo + sg;
    for (; it + 3L * SPG < hi; it += 4L * SPG) {
        float2 r0 = rec[it];
        float2 r1 = rec[it + SPG];
        float2 r2 = rec[it + 2L * SPG];
        float2 r3 = rec[it + 3L * SPG];
        unsigned p0 = (unsigned)__float_as_int(r0.y), p1 = (unsigned)__float_as_int(r1.y);
        unsigned p2 = (unsigned)__float_as_int(r2.y), p3 = (unsigned)__float_as_int(r3.y);
        float4 v0 = hs4[(long)(p0 & 0x1FFFFu) * 8 + z4];
        float4 v1 = hs4[(long)(p1 & 0x1FFFFu) * 8 + z4];
        float4 v2 = hs4[(long)(p2 & 0x1FFFFu) * 8 + z4];
        float4 v3 = hs4[(long)(p3 & 0x1FFFFu) * 8 + z4];
        float c0 = r0.x * (inl ? dl[p0 >> 17] : dinv[ns + (p0 >> 17)]);
        float c1 = r1.x * (inl ? dl[p1 >> 17] : dinv[ns + (p1 >> 17)]);
        float c2 = r2.x * (inl ? dl[p2 >> 17] : dinv[ns + (p2 >> 17)]);
        float c3 = r3.x * (inl ? dl[p3 >> 17] : dinv[ns + (p3 >> 17)]);
        acc.x = fmaf(c0, v0.x, acc.x); acc.y = fmaf(c0, v0.y, acc.y);
        acc.z = fmaf(c0, v0.z, acc.z); acc.w = fmaf(c0, v0.w, acc.w);
        acc.x = fmaf(c1, v1.x, acc.x); acc.y = fmaf(c1, v1.y, acc.y);
        acc.z = fmaf(c1, v1.z, acc.z); acc.w = fmaf(c1, v1.w, acc.w);
        acc.x = fmaf(c2, v2.x, acc.x); acc.y = fmaf(c2, v2.y, acc.y);
        acc.z = fmaf(c2, v2.z, acc.z); acc.w = fmaf(c2, v2.w, acc.w);
        acc.x = fmaf(c3, v3.x, acc.x); acc.y = fmaf(c3, v3.y, acc.y);
        acc.z = fmaf(c3, v3.z, acc.z); acc.w = fmaf(c3, v3.w, acc.w);
    }
    for (; it < hi; it += SPG) {
        float2 r = rec[it];
        unsigned p = (unsigned)__float_as_int(r.y);
        float4 v = hs4[(long)(p & 0x1FFFFu) * 8 + z4];
        float c = r.x * (inl ? dl[p >> 17] : dinv[ns + (p >> 17)]);
        acc.x = fmaf(c, v.x, acc.x); acc.y = fmaf(c, v.y, acc.y);
        acc.z = fmaf(c, v.z, acc.z); acc.w = fmaf(c, v.w, acc.w);
    }

    // self-loops: nodes of graph g are contiguous [ns, ne)
    for (long i = ns + sg; i < ne; i += SPG) {
        float c2v = 2.0f * (inl ? dl[i - ns] : dinv[i]);
        float4 v = hs4[i * 8 + z4];
        acc.x = fmaf(c2v, v.x, acc.x); acc.y = fmaf(c2v, v.y, acc.y);
        acc.z = fmaf(c2v, v.z, acc.z); acc.w = fmaf(c2v, v.w, acc.w);
    }

    // reduce 64 slots -> 32 channels
    __shared__ float4 s[SLOTS][8];
    __shared__ float4 s2[8][8];
    s[slot][z4] = acc;
    __syncthreads();
    if (threadIdx.x < 64) {
        int j = threadIdx.x & 7, part = threadIdx.x >> 3;
        float4 a = make_float4(0.f, 0.f, 0.f, 0.f);
#pragma unroll
        for (int k = 0; k < 8; ++k) {
            float4 b = s[part * 8 + k][j];
            a.x += b.x; a.y += b.y; a.z += b.z; a.w += b.w;
        }
        s2[part][j] = a;
    }
    __syncthreads();
    if (threadIdx.x < 8) {
        int j = threadIdx.x;
        float4 a = make_float4(0.f, 0.f, 0.f, 0.f);
#pragma unroll
        for (int k = 0; k < 8; ++k) {
            float4 b = s2[k][j];
            a.x += b.x; a.y += b.y; a.z += b.z; a.w += b.w;
        }
        *(float4*)&partial[(long)blockIdx.x * ZZDIM + j * 4] = a;
    }
}

// sum BPG partials per graph -> pooled -> logits
__global__ void finalize_kernel(const float* __restrict__ partial, const int* __restrict__ lb,
                                const float* __restrict__ bc, const float* __restrict__ Wr,
                                float* __restrict__ out) {
    int g = blockIdx.x;
    int t = threadIdx.x;  // 64 threads
    __shared__ float p[ZZDIM];
    if (t < ZZDIM) {
        float a = 0.f;
#pragma unroll
        for (int q = 0; q < BPG; ++q) a += partial[(long)(g * BPG + q) * ZZDIM + t];
        float c = (float)(lb[g + 1] - lb[g]);
        float v = (c > 0.f) ? (bc[t] + a / c) : 0.f;
        out[g * ZZDIM + t] = v;
        p[t] = v;
    }
    __syncthreads();
    float a = 0.f;
#pragma unroll
    for (int zz = 0; zz < ZZDIM; ++zz) a += p[zz] * Wr[zz * KK + t];
    out[GG * ZZDIM + g * KK + t] = a;
}

// ---------------- launch ----------------

extern "C" void kernel_launch(void* const* d_in, const int* in_sizes, int n_in,
                              void* d_out, int out_size, void* d_ws, size_t ws_size,
                              hipStream_t stream) {
    const int*   x     = (const int*)d_in[0];
    const int*   ei    = (const int*)d_in[1];   // [2,E]: rows then cols
    const float* ew    = (const float*)d_in[2];
    const int*   batch = (const int*)d_in[3];
    const float* emb   = (const float*)d_in[4];
    const float* Wc    = (const float*)d_in[5];
    const float* bc    = (const float*)d_in[6];
    const float* Wr    = (const float*)d_in[7];
    float* out = (float*)d_out;

    const int n = in_sizes[0];
    const int e = in_sizes[2];

    float* ws   = (float*)d_ws;
    float* hs   = ws;                        // 32n (16 B-aligned: base of ws)
    float* dinv = ws + 32L * n;              // n
    int*  lb    = (int*)(ws + 33L * n);      // GG+1
    int*  gcnt  = lb + GG + 1;               // GG
    int*  gbase = gcnt + GG;                 // GG+1
    int*  gcur  = gbase + GG + 1;            // GG
    long base = 33L * n + (4 * GG + 2);
    base = (base + 63) & ~63L;
    unsigned char* ge = (unsigned char*)(ws + base);  // e bytes
    long rbase = base + (e + 3) / 4;
    rbase = (rbase + 63) & ~63L;
    float2* rec = (float2*)(ws + rbase);     // e records (8 B)
    long pbase = rbase + 2L * e;
    pbase = (pbase + 63) & ~63L;
    float* partial = ws + pbase;             // SGRID*32 floats

    lb_kernel<<<1, 256, 0, stream>>>(batch, lb, gcnt, n);
    hist_kernel<<<256, 256, 0, stream>>>(ei + e, batch, ge, gcnt, e);
    scan_kernel<<<1, 64, 0, stream>>>(gcnt, gbase, gcur);
    bucket_kernel<<<(e + 8191) / 8192, 512, 0, stream>>>(ei, ei + e, ew, ge, lb, gcur, rec, e);
    degB_kernel<<<GG, 256, 0, stream>>>(rec, gbase, lb, dinv);
    hs_kernel<<<(n * 32 + 255) / 256, 256, 0, stream>>>(x, emb, Wc, dinv, hs, n);
    scatter_kernel<<<SGRID, 512, 0, stream>>>(rec, gbase, lb, dinv, (const float4*)hs, partial);
    finalize_kernel<<<GG, KK, 0, stream>>>(partial, lb, bc, Wr, out);
}

// Round 9
// 104.475 us; speedup vs baseline: 4.2905x; 1.0809x over previous
//
#include <hip/hip_runtime.h>
#include <hip/hip_fp16.h>

#define GG 256   // NUM_GRAPHS
#define ZZDIM 32 // Z
#define KK 64    // K
#define EMBD 10  // EMB
#define BPG 4                // scatter blocks per graph
#define SGRID (GG * BPG)     // 1024 scatter blocks
#define SLOTS 64             // slots per 512-thr scatter block (8 lanes each)
#define SPG (BPG * SLOTS)    // 256 slots per graph
#define MAXN 4096            // LDS node-slice capacity (graphs avg ~390 nodes)

// Record: rec[i] = (w, bits(colLocal<<17 | row)); row < 2^17 (n=100000), colLocal < 2^15.
// hs is fp16: 32 ch x 2B = 64 B per node row; quantization error ~1.5e-4/elem,
// pooled error ~5e-6 << 2.1e-3 threshold.

// ---------------- kernels ----------------

// node ranges per graph via binary search on sorted batch; zero bucket counters
__global__ void lb_kernel(const int* __restrict__ batch, int* __restrict__ lb,
                          int* __restrict__ gcnt, int n) {
    int g = threadIdx.x;  // 256 threads
    int lo = 0, hi = n;
    while (lo < hi) {
        int mid = (lo + hi) >> 1;
        if (batch[mid] < g) lo = mid + 1; else hi = mid;
    }
    lb[g] = lo;
    if (g == 0) lb[GG] = n;
    gcnt[g] = 0;
}

// per-graph edge histogram; memoize g per edge (ge) for the bucket pass
__global__ void hist_kernel(const int* __restrict__ col, const int* __restrict__ batch,
                            unsigned char* __restrict__ ge, int* __restrict__ gcnt, int e) {
    __shared__ int h[GG];
    if (threadIdx.x < GG) h[threadIdx.x] = 0;
    __syncthreads();
    for (long i = blockIdx.x * (long)blockDim.x + threadIdx.x; i < e;
         i += (long)gridDim.x * blockDim.x) {
        int g = batch[col[i]];
        ge[i] = (unsigned char)g;
        atomicAdd(&h[g], 1);
    }
    __syncthreads();
    if (threadIdx.x < GG && h[threadIdx.x])
        atomicAdd(&gcnt[threadIdx.x], h[threadIdx.x]);
}

// exclusive scan of 256 bucket counts; init cursors
__global__ void scan_kernel(const int* __restrict__ gcnt, int* __restrict__ gbase,
                            int* __restrict__ gcur) {
    if (threadIdx.x == 0) {
        int s = 0;
        for (int g = 0; g < GG; ++g) { gbase[g] = s; gcur[g] = s; s += gcnt[g]; }
        gbase[GG] = s;
    }
}

// counting-sort edges into per-graph buckets: rec = (w, bits(colLocal<<17|row))
__global__ void __launch_bounds__(512) bucket_kernel(
    const int* __restrict__ row, const int* __restrict__ col, const float* __restrict__ w,
    const unsigned char* __restrict__ ge, const int* __restrict__ lb,
    int* __restrict__ gcur, float2* __restrict__ rec, int e) {
    __shared__ int lcnt[GG], lres[GG], loff[GG], lbs[GG];
    for (int t = threadIdx.x; t < GG; t += 512) { lcnt[t] = 0; loff[t] = 0; lbs[t] = lb[t]; }
    __syncthreads();
    const long start = (long)blockIdx.x * 8192;
    int myg[16];
#pragma unroll
    for (int k = 0; k < 16; ++k) {
        long i = start + k * 512 + threadIdx.x;
        int g = -1;
        if (i < e) { g = ge[i]; atomicAdd(&lcnt[g], 1); }
        myg[k] = g;
    }
    __syncthreads();
    for (int t = threadIdx.x; t < GG; t += 512)
        if (lcnt[t]) lres[t] = atomicAdd(&gcur[t], lcnt[t]);
    __syncthreads();
#pragma unroll
    for (int k = 0; k < 16; ++k) {
        long i = start + k * 512 + threadIdx.x;
        if (i < e) {
            int g = myg[k];
            int slot = lres[g] + atomicAdd(&loff[g], 1);
            unsigned p = ((unsigned)(col[i] - lbs[g]) << 17) | (unsigned)row[i];
            rec[slot] = make_float2(w[i], __int_as_float((int)p));
        }
    }
}

// per-graph degree via LDS accumulation over the graph's contiguous node slice;
// writes dinv = rsqrt(deg). One block per graph — NO device-scope atomics.
__global__ void degB_kernel(const float2* __restrict__ rec, const int* __restrict__ gbase,
                            const int* __restrict__ lb, float* __restrict__ dinv) {
    __shared__ float dl[MAXN];
    const int g = blockIdx.x;
    const int ns = lb[g], ne = lb[g + 1], sz = ne - ns;
    const long lo = gbase[g], hi = gbase[g + 1];
    if (sz <= MAXN) {
        for (int t = threadIdx.x; t < sz; t += 256) dl[t] = 2.0f;  // improved self-loop fill
        __syncthreads();
        for (long it = lo + threadIdx.x; it < hi; it += 256) {
            float2 r = rec[it];
            atomicAdd(&dl[(unsigned)__float_as_int(r.y) >> 17], r.x);
        }
        __syncthreads();
        for (int t = threadIdx.x; t < sz; t += 256) dinv[ns + t] = rsqrtf(dl[t]);
    } else {  // fallback (never expected at n/GG ~ 390)
        for (int t = threadIdx.x; t < sz; t += 256) dinv[ns + t] = 2.0f;
        __syncthreads();
        for (long it = lo + threadIdx.x; it < hi; it += 256) {
            float2 r = rec[it];
            atomicAdd(&dinv[ns + ((unsigned)__float_as_int(r.y) >> 17)], r.x);
        }
        __syncthreads();
        for (int t = threadIdx.x; t < sz; t += 256) dinv[ns + t] = rsqrtf(dinv[ns + t]);
    }
}

// hs16[i, 2zp..2zp+1] = half2( dinv[i] * sum_j embed[x[i],j] * Wc[j, 2zp..2zp+1] )
__global__ void hs_kernel(const int* __restrict__ x, const float* __restrict__ emb,
                          const float* __restrict__ Wc, const float* __restrict__ dinv,
                          __half2* __restrict__ hs16, int n) {
    int tid = blockIdx.x * blockDim.x + threadIdx.x;
    int i = tid >> 4, zp = tid & 15;     // 16 half2 per node row
    if (i >= n) return;
    float d = dinv[i];
    int xi = x[i];
    const float* er = emb + (long)xi * EMBD;
    float a0 = 0.f, a1 = 0.f;
#pragma unroll
    for (int j = 0; j < EMBD; ++j) {
        float ej = er[j];
        a0 += ej * Wc[j * ZZDIM + 2 * zp];
        a1 += ej * Wc[j * ZZDIM + 2 * zp + 1];
    }
    hs16[(long)i * 16 + zp] = __floats2half2_rn(d * a0, d * a1);
}

// Register-accumulation scatter over fp16 hs rows (64 B): 8 lanes x uint2 per edge.
__global__ void __launch_bounds__(512) scatter_kernel(
    const float2* __restrict__ rec, const int* __restrict__ gbase,
    const int* __restrict__ lb, const float* __restrict__ dinv,
    const uint2* __restrict__ hsq, float* __restrict__ partial) {
    __shared__ float dl[MAXN];
    const int z4   = threadIdx.x & 7;        // channel quad 0..7
    const int slot = threadIdx.x >> 3;       // 0..63
    const int g = blockIdx.x >> 2;
    const int q = blockIdx.x & 3;
    const int sg = q * SLOTS + slot;         // slot-in-graph 0..255
    const int ns = lb[g], ne = lb[g + 1], sz = ne - ns;
    const bool inl = (sz <= MAXN);
    if (inl) for (int t = threadIdx.x; t < sz; t += 512) dl[t] = dinv[ns + t];
    __syncthreads();

    float4 acc = make_float4(0.f, 0.f, 0.f, 0.f);

#define GATHER4(pp) hsq[(long)((pp) & 0x1FFFFu) * 8 + z4]
#define ACCUM(c, v) do {                                              \
        float2 f0 = __half22float2(*(const __half2*)&(v).x);          \
        float2 f1 = __half22float2(*(const __half2*)&(v).y);          \
        acc.x = fmaf((c), f0.x, acc.x); acc.y = fmaf((c), f0.y, acc.y);\
        acc.z = fmaf((c), f1.x, acc.z); acc.w = fmaf((c), f1.y, acc.w);\
    } while (0)

    // edges of graph g (bucketed, contiguous)
    const long lo = gbase[g], hi = gbase[g + 1];
    long it = lo + sg;
    for (; it + 3L * SPG < hi; it += 4L * SPG) {
        float2 r0 = rec[it];
        float2 r1 = rec[it + SPG];
        float2 r2 = rec[it + 2L * SPG];
        float2 r3 = rec[it + 3L * SPG];
        unsigned p0 = (unsigned)__float_as_int(r0.y), p1 = (unsigned)__float_as_int(r1.y);
        unsigned p2 = (unsigned)__float_as_int(r2.y), p3 = (unsigned)__float_as_int(r3.y);
        uint2 v0 = GATHER4(p0);
        uint2 v1 = GATHER4(p1);
        uint2 v2 = GATHER4(p2);
        uint2 v3 = GATHER4(p3);
        float c0 = r0.x * (inl ? dl[p0 >> 17] : dinv[ns + (p0 >> 17)]);
        float c1 = r1.x * (inl ? dl[p1 >> 17] : dinv[ns + (p1 >> 17)]);
        float c2 = r2.x * (inl ? dl[p2 >> 17] : dinv[ns + (p2 >> 17)]);
        float c3 = r3.x * (inl ? dl[p3 >> 17] : dinv[ns + (p3 >> 17)]);
        ACCUM(c0, v0); ACCUM(c1, v1); ACCUM(c2, v2); ACCUM(c3, v3);
    }
    for (; it < hi; it += SPG) {
        float2 r = rec[it];
        unsigned p = (unsigned)__float_as_int(r.y);
        uint2 v = GATHER4(p);
        float c = r.x * (inl ? dl[p >> 17] : dinv[ns + (p >> 17)]);
        ACCUM(c, v);
    }

    // self-loops: nodes of graph g are contiguous [ns, ne)
    for (long i = ns + sg; i < ne; i += SPG) {
        float c2v = 2.0f * (inl ? dl[i - ns] : dinv[i]);
        uint2 v = hsq[i * 8 + z4];
        ACCUM(c2v, v);
    }
#undef GATHER4
#undef ACCUM

    // reduce 64 slots -> 32 channels
    __shared__ float4 s[SLOTS][8];
    __shared__ float4 s2[8][8];
    s[slot][z4] = acc;
    __syncthreads();
    if (threadIdx.x < 64) {
        int j = threadIdx.x & 7, part = threadIdx.x >> 3;
        float4 a = make_float4(0.f, 0.f, 0.f, 0.f);
#pragma unroll
        for (int k = 0; k < 8; ++k) {
            float4 b = s[part * 8 + k][j];
            a.x += b.x; a.y += b.y; a.z += b.z; a.w += b.w;
        }
        s2[part][j] = a;
    }
    __syncthreads();
    if (threadIdx.x < 8) {
        int j = threadIdx.x;
        float4 a = make_float4(0.f, 0.f, 0.f, 0.f);
#pragma unroll
        for (int k = 0; k < 8; ++k) {
            float4 b = s2[k][j];
            a.x += b.x; a.y += b.y; a.z += b.z; a.w += b.w;
        }
        *(float4*)&partial[(long)blockIdx.x * ZZDIM + j * 4] = a;
    }
}

// sum BPG partials per graph -> pooled -> logits
__global__ void finalize_kernel(const float* __restrict__ partial, const int* __restrict__ lb,
                                const float* __restrict__ bc, const float* __restrict__ Wr,
                                float* __restrict__ out) {
    int g = blockIdx.x;
    int t = threadIdx.x;  // 64 threads
    __shared__ float p[ZZDIM];
    if (t < ZZDIM) {
        float a = 0.f;
#pragma unroll
        for (int q = 0; q < BPG; ++q) a += partial[(long)(g * BPG + q) * ZZDIM + t];
        float c = (float)(lb[g + 1] - lb[g]);
        float v = (c > 0.f) ? (bc[t] + a / c) : 0.f;
        out[g * ZZDIM + t] = v;
        p[t] = v;
    }
    __syncthreads();
    float a = 0.f;
#pragma unroll
    for (int zz = 0; zz < ZZDIM; ++zz) a += p[zz] * Wr[zz * KK + t];
    out[GG * ZZDIM + g * KK + t] = a;
}

// ---------------- launch ----------------

extern "C" void kernel_launch(void* const* d_in, const int* in_sizes, int n_in,
                              void* d_out, int out_size, void* d_ws, size_t ws_size,
                              hipStream_t stream) {
    const int*   x     = (const int*)d_in[0];
    const int*   ei    = (const int*)d_in[1];   // [2,E]: rows then cols
    const float* ew    = (const float*)d_in[2];
    const int*   batch = (const int*)d_in[3];
    const float* emb   = (const float*)d_in[4];
    const float* Wc    = (const float*)d_in[5];
    const float* bc    = (const float*)d_in[6];
    const float* Wr    = (const float*)d_in[7];
    float* out = (float*)d_out;

    const int n = in_sizes[0];
    const int e = in_sizes[2];

    float* ws   = (float*)d_ws;
    __half2* hs16 = (__half2*)ws;            // n*16 half2 = 16n floats (16 B aligned)
    float* dinv = ws + 16L * n;              // n
    int*  lb    = (int*)(ws + 17L * n);      // GG+1
    int*  gcnt  = lb + GG + 1;               // GG
    int*  gbase = gcnt + GG;                 // GG+1
    int*  gcur  = gbase + GG + 1;            // GG
    long base = 17L * n + (4 * GG + 2);
    base = (base + 63) & ~63L;
    unsigned char* ge = (unsigned char*)(ws + base);  // e bytes
    long rbase = base + (e + 3) / 4;
    rbase = (rbase + 63) & ~63L;
    float2* rec = (float2*)(ws + rbase);     // e records (8 B)
    long pbase = rbase + 2L * e;
    pbase = (pbase + 63) & ~63L;
    float* partial = ws + pbase;             // SGRID*32 floats

    lb_kernel<<<1, 256, 0, stream>>>(batch, lb, gcnt, n);
    hist_kernel<<<256, 256, 0, stream>>>(ei + e, batch, ge, gcnt, e);
    scan_kernel<<<1, 64, 0, stream>>>(gcnt, gbase, gcur);
    bucket_kernel<<<(e + 8191) / 8192, 512, 0, stream>>>(ei, ei + e, ew, ge, lb, gcur, rec, e);
    degB_kernel<<<GG, 256, 0, stream>>>(rec, gbase, lb, dinv);
    hs_kernel<<<(n * 16 + 255) / 256, 256, 0, stream>>>(x, emb, Wc, dinv, hs16, n);
    scatter_kernel<<<SGRID, 512, 0, stream>>>(rec, gbase, lb, dinv, (const uint2*)hs16, partial);
    finalize_kernel<<<GG, KK, 0, stream>>>(partial, lb, bc, Wr, out);
}

// Round 10
// 85.045 us; speedup vs baseline: 5.2707x; 1.2285x over previous
//
#include <hip/hip_runtime.h>
#include <hip/hip_fp16.h>

#define GG 256   // NUM_GRAPHS
#define ZZDIM 32 // Z
#define KK 64    // K
#define EMBD 10  // EMB
#define BPG 4                // scatter blocks per graph
#define SGRID (GG * BPG)     // 1024 scatter blocks
#define SLOTS 64             // slots per 512-thr scatter block (8 lanes each)
#define SPG (BPG * SLOTS)    // 256 slots per graph
#define MAXN 4096            // LDS node-slice capacity (graphs avg ~390 nodes)
#define CAP 16384            // per-graph record segment capacity (avg fill 6250, 24+ sigma margin)

// Record: rec[i] = (w, bits(colLocal<<17 | row)); row < 2^17 (n=100000), colLocal < 2^15.
// hs is fp16: one 64 B line per node row — each edge gather touches exactly one line.

// ---------------- kernels ----------------

// node ranges per graph via binary search on sorted batch; init segment cursors
__global__ void lb_kernel(const int* __restrict__ batch, int* __restrict__ lb,
                          int* __restrict__ gcur, int n) {
    int g = threadIdx.x;  // 256 threads
    int lo = 0, hi = n;
    while (lo < hi) {
        int mid = (lo + hi) >> 1;
        if (batch[mid] < g) lo = mid + 1; else hi = mid;
    }
    lb[g] = lo;
    if (g == 0) lb[GG] = n;
    gcur[g] = g * CAP;
}

// single-pass counting-bucket: g = batch[col] inline (L2-hit), block-run reservation
// via 256 global cursor atomics, records into fixed-capacity per-graph segments.
__global__ void __launch_bounds__(512) bucket_kernel(
    const int* __restrict__ row, const int* __restrict__ col, const float* __restrict__ w,
    const int* __restrict__ batch, const int* __restrict__ lb,
    int* __restrict__ gcur, float2* __restrict__ rec, int e) {
    __shared__ int lcnt[GG], lres[GG], loff[GG], lbs[GG];
    for (int t = threadIdx.x; t < GG; t += 512) { lcnt[t] = 0; loff[t] = 0; lbs[t] = lb[t]; }
    __syncthreads();
    const long start = (long)blockIdx.x * 8192;
    int myg[16]; unsigned myp[16];
#pragma unroll
    for (int k = 0; k < 16; ++k) {
        long i = start + k * 512 + threadIdx.x;
        int g = -1;
        if (i < e) {
            int c = col[i];
            g = batch[c];
            myp[k] = ((unsigned)(c - lbs[g]) << 17) | (unsigned)row[i];
            atomicAdd(&lcnt[g], 1);
        }
        myg[k] = g;
    }
    __syncthreads();
    for (int t = threadIdx.x; t < GG; t += 512)
        if (lcnt[t]) lres[t] = atomicAdd(&gcur[t], lcnt[t]);
    __syncthreads();
#pragma unroll
    for (int k = 0; k < 16; ++k) {
        long i = start + k * 512 + threadIdx.x;
        if (i < e) {
            int g = myg[k];
            int slot = lres[g] + atomicAdd(&loff[g], 1);
            rec[slot] = make_float2(w[i], __int_as_float((int)myp[k]));
        }
    }
}

// per-graph degree via LDS accumulation over the graph's contiguous node slice;
// writes dinv = rsqrt(deg). One block per graph — NO device-scope atomics.
__global__ void degB_kernel(const float2* __restrict__ rec, const int* __restrict__ gcur,
                            const int* __restrict__ lb, float* __restrict__ dinv) {
    __shared__ float dl[MAXN];
    const int g = blockIdx.x;
    const int ns = lb[g], ne = lb[g + 1], sz = ne - ns;
    const long lo = (long)g * CAP;
    const long hi = gcur[g];
    if (sz <= MAXN) {
        for (int t = threadIdx.x; t < sz; t += 256) dl[t] = 2.0f;  // improved self-loop fill
        __syncthreads();
        for (long it = lo + threadIdx.x; it < hi; it += 256) {
            float2 r = rec[it];
            atomicAdd(&dl[(unsigned)__float_as_int(r.y) >> 17], r.x);
        }
        __syncthreads();
        for (int t = threadIdx.x; t < sz; t += 256) dinv[ns + t] = rsqrtf(dl[t]);
    } else {  // fallback (never expected at n/GG ~ 390)
        for (int t = threadIdx.x; t < sz; t += 256) dinv[ns + t] = 2.0f;
        __syncthreads();
        for (long it = lo + threadIdx.x; it < hi; it += 256) {
            float2 r = rec[it];
            atomicAdd(&dinv[ns + ((unsigned)__float_as_int(r.y) >> 17)], r.x);
        }
        __syncthreads();
        for (int t = threadIdx.x; t < sz; t += 256) dinv[ns + t] = rsqrtf(dinv[ns + t]);
    }
}

// hs16[i, 2zp..2zp+1] = half2( dinv[i] * sum_j embed[x[i],j] * Wc[j, 2zp..2zp+1] )
__global__ void hs_kernel(const int* __restrict__ x, const float* __restrict__ emb,
                          const float* __restrict__ Wc, const float* __restrict__ dinv,
                          __half2* __restrict__ hs16, int n) {
    int tid = blockIdx.x * blockDim.x + threadIdx.x;
    int i = tid >> 4, zp = tid & 15;     // 16 half2 per node row
    if (i >= n) return;
    float d = dinv[i];
    int xi = x[i];
    const float* er = emb + (long)xi * EMBD;
    float a0 = 0.f, a1 = 0.f;
#pragma unroll
    for (int j = 0; j < EMBD; ++j) {
        float ej = er[j];
        a0 += ej * Wc[j * ZZDIM + 2 * zp];
        a1 += ej * Wc[j * ZZDIM + 2 * zp + 1];
    }
    hs16[(long)i * 16 + zp] = __floats2half2_rn(d * a0, d * a1);
}

// Register-accumulation scatter over fp16 hs rows (64 B): 8 lanes x uint2 per edge.
__global__ void __launch_bounds__(512) scatter_kernel(
    const float2* __restrict__ rec, const int* __restrict__ gcur,
    const int* __restrict__ lb, const float* __restrict__ dinv,
    const uint2* __restrict__ hsq, float* __restrict__ partial) {
    __shared__ float dl[MAXN];
    const int z4   = threadIdx.x & 7;        // channel quad 0..7
    const int slot = threadIdx.x >> 3;       // 0..63
    const int g = blockIdx.x >> 2;
    const int q = blockIdx.x & 3;
    const int sg = q * SLOTS + slot;         // slot-in-graph 0..255
    const int ns = lb[g], ne = lb[g + 1], sz = ne - ns;
    const bool inl = (sz <= MAXN);
    if (inl) for (int t = threadIdx.x; t < sz; t += 512) dl[t] = dinv[ns + t];
    __syncthreads();

    float4 acc = make_float4(0.f, 0.f, 0.f, 0.f);

#define GATHER4(pp) hsq[(long)((pp) & 0x1FFFFu) * 8 + z4]
#define ACCUM(c, v) do {                                              \
        float2 f0 = __half22float2(*(const __half2*)&(v).x);          \
        float2 f1 = __half22float2(*(const __half2*)&(v).y);          \
        acc.x = fmaf((c), f0.x, acc.x); acc.y = fmaf((c), f0.y, acc.y);\
        acc.z = fmaf((c), f1.x, acc.z); acc.w = fmaf((c), f1.y, acc.w);\
    } while (0)

    // edges of graph g (bucketed segment [g*CAP, gcur[g]))
    const long lo = (long)g * CAP;
    const long hi = gcur[g];
    long it = lo + sg;
    for (; it + 3L * SPG < hi; it += 4L * SPG) {
        float2 r0 = rec[it];
        float2 r1 = rec[it + SPG];
        float2 r2 = rec[it + 2L * SPG];
        float2 r3 = rec[it + 3L * SPG];
        unsigned p0 = (unsigned)__float_as_int(r0.y), p1 = (unsigned)__float_as_int(r1.y);
        unsigned p2 = (unsigned)__float_as_int(r2.y), p3 = (unsigned)__float_as_int(r3.y);
        uint2 v0 = GATHER4(p0);
        uint2 v1 = GATHER4(p1);
        uint2 v2 = GATHER4(p2);
        uint2 v3 = GATHER4(p3);
        float c0 = r0.x * (inl ? dl[p0 >> 17] : dinv[ns + (p0 >> 17)]);
        float c1 = r1.x * (inl ? dl[p1 >> 17] : dinv[ns + (p1 >> 17)]);
        float c2 = r2.x * (inl ? dl[p2 >> 17] : dinv[ns + (p2 >> 17)]);
        float c3 = r3.x * (inl ? dl[p3 >> 17] : dinv[ns + (p3 >> 17)]);
        ACCUM(c0, v0); ACCUM(c1, v1); ACCUM(c2, v2); ACCUM(c3, v3);
    }
    for (; it < hi; it += SPG) {
        float2 r = rec[it];
        unsigned p = (unsigned)__float_as_int(r.y);
        uint2 v = GATHER4(p);
        float c = r.x * (inl ? dl[p >> 17] : dinv[ns + (p >> 17)]);
        ACCUM(c, v);
    }

    // self-loops: nodes of graph g are contiguous [ns, ne)
    for (long i = ns + sg; i < ne; i += SPG) {
        float c2v = 2.0f * (inl ? dl[i - ns] : dinv[i]);
        uint2 v = hsq[i * 8 + z4];
        ACCUM(c2v, v);
    }
#undef GATHER4
#undef ACCUM

    // reduce 64 slots -> 32 channels
    __shared__ float4 s[SLOTS][8];
    __shared__ float4 s2[8][8];
    s[slot][z4] = acc;
    __syncthreads();
    if (threadIdx.x < 64) {
        int j = threadIdx.x & 7, part = threadIdx.x >> 3;
        float4 a = make_float4(0.f, 0.f, 0.f, 0.f);
#pragma unroll
        for (int k = 0; k < 8; ++k) {
            float4 b = s[part * 8 + k][j];
            a.x += b.x; a.y += b.y; a.z += b.z; a.w += b.w;
        }
        s2[part][j] = a;
    }
    __syncthreads();
    if (threadIdx.x < 8) {
        int j = threadIdx.x;
        float4 a = make_float4(0.f, 0.f, 0.f, 0.f);
#pragma unroll
        for (int k = 0; k < 8; ++k) {
            float4 b = s2[k][j];
            a.x += b.x; a.y += b.y; a.z += b.z; a.w += b.w;
        }
        *(float4*)&partial[(long)blockIdx.x * ZZDIM + j * 4] = a;
    }
}

// sum BPG partials per graph -> pooled -> logits
__global__ void finalize_kernel(const float* __restrict__ partial, const int* __restrict__ lb,
                                const float* __restrict__ bc, const float* __restrict__ Wr,
                                float* __restrict__ out) {
    int g = blockIdx.x;
    int t = threadIdx.x;  // 64 threads
    __shared__ float p[ZZDIM];
    if (t < ZZDIM) {
        float a = 0.f;
#pragma unroll
        for (int q = 0; q < BPG; ++q) a += partial[(long)(g * BPG + q) * ZZDIM + t];
        float c = (float)(lb[g + 1] - lb[g]);
        float v = (c > 0.f) ? (bc[t] + a / c) : 0.f;
        out[g * ZZDIM + t] = v;
        p[t] = v;
    }
    __syncthreads();
    float a = 0.f;
#pragma unroll
    for (int zz = 0; zz < ZZDIM; ++zz) a += p[zz] * Wr[zz * KK + t];
    out[GG * ZZDIM + g * KK + t] = a;
}

// ---------------- launch ----------------

extern "C" void kernel_launch(void* const* d_in, const int* in_sizes, int n_in,
                              void* d_out, int out_size, void* d_ws, size_t ws_size,
                              hipStream_t stream) {
    const int*   x     = (const int*)d_in[0];
    const int*   ei    = (const int*)d_in[1];   // [2,E]: rows then cols
    const float* ew    = (const float*)d_in[2];
    const int*   batch = (const int*)d_in[3];
    const float* emb   = (const float*)d_in[4];
    const float* Wc    = (const float*)d_in[5];
    const float* bc    = (const float*)d_in[6];
    const float* Wr    = (const float*)d_in[7];
    float* out = (float*)d_out;

    const int n = in_sizes[0];
    const int e = in_sizes[2];

    float* ws   = (float*)d_ws;
    __half2* hs16 = (__half2*)ws;            // n*16 half2 = 16n words (16 B aligned)
    float* dinv = ws + 16L * n;              // n
    int*  lb    = (int*)(ws + 17L * n);      // GG+1
    int*  gcur  = lb + GG + 1;               // GG
    long rbase = 17L * n + (2 * GG + 1);
    rbase = (rbase + 63) & ~63L;
    float2* rec = (float2*)(ws + rbase);     // GG*CAP records (8 B each)
    long pbase = rbase + 2L * GG * CAP;
    pbase = (pbase + 63) & ~63L;
    float* partial = ws + pbase;             // SGRID*32 floats

    lb_kernel<<<1, 256, 0, stream>>>(batch, lb, gcur, n);
    bucket_kernel<<<(e + 8191) / 8192, 512, 0, stream>>>(ei, ei + e, ew, batch, lb, gcur, rec, e);
    degB_kernel<<<GG, 256, 0, stream>>>(rec, gcur, lb, dinv);
    hs_kernel<<<(n * 16 + 255) / 256, 256, 0, stream>>>(x, emb, Wc, dinv, hs16, n);
    scatter_kernel<<<SGRID, 512, 0, stream>>>(rec, gcur, lb, dinv, (const uint2*)hs16, partial);
    finalize_kernel<<<GG, KK, 0, stream>>>(partial, lb, bc, Wr, out);
}